// Round 6
// baseline (254.064 us; speedup 1.0000x reference)
//
#include <hip/hip_runtime.h>

#define BATCH 8
#define SDIM 2048
#define KDIM 2048
#define NDIM 2048

typedef __bf16 bf16_t;
typedef bf16_t bf16x4 __attribute__((ext_vector_type(4)));
typedef bf16_t bf16x8 __attribute__((ext_vector_type(8)));
typedef float f32x4 __attribute__((ext_vector_type(4)));
typedef float f32x8 __attribute__((ext_vector_type(8)));
typedef unsigned short u16x8 __attribute__((ext_vector_type(8)));

__device__ __forceinline__ void gl_lds16(const void* g, void* l) {
    // async global->LDS DMA, 16B/lane; LDS dest = wave-uniform base + lane*16
    __builtin_amdgcn_global_load_lds(
        (__attribute__((address_space(1))) void*)g,
        (__attribute__((address_space(3))) void*)l,
        16, 0, 0);
}

// ---------------- Pass 1a: A fp32 -> bf16 (elementwise) ----------------
__global__ __launch_bounds__(256)
void cvtA_kernel(const float* __restrict__ A, bf16_t* __restrict__ Abf) {
    const size_t total8 = (size_t)BATCH * SDIM * KDIM / 8;
    const size_t stride = (size_t)gridDim.x * 256;
    for (size_t i = (size_t)blockIdx.x * 256 + threadIdx.x; i < total8; i += stride) {
        f32x8 v = *reinterpret_cast<const f32x8*>(A + i * 8);
        *reinterpret_cast<bf16x8*>(Abf + i * 8) = __builtin_convertvector(v, bf16x8);
    }
}

// ------------- Pass 1b: B fp32 [K][N] -> bf16 B^T [N][K] ----------------
__global__ __launch_bounds__(256)
void cvtBT_kernel(const float* __restrict__ B, bf16_t* __restrict__ Bt) {
    __shared__ alignas(16) bf16_t T[64][72];
    const int gid = blockIdx.x;
    const int batch = gid & 7;
    const int tile = gid >> 3;
    const int k0g = (tile >> 5) * 64;
    const int n0g = (tile & 31) * 64;
    const float* Bb = B + (size_t)batch * KDIM * NDIM + (size_t)k0g * NDIM + n0g;
    bf16_t* Tb = Bt + (size_t)batch * NDIM * KDIM + (size_t)n0g * KDIM + k0g;

    const int t = threadIdx.x;
    const int kq = t & 15;
    const int nq = t >> 4;
    f32x4 v[4];
#pragma unroll
    for (int r = 0; r < 4; ++r)
        v[r] = *reinterpret_cast<const f32x4*>(Bb + (size_t)(kq * 4 + r) * NDIM + nq * 4);
#pragma unroll
    for (int j = 0; j < 4; ++j) {
        bf16x4 w = {(bf16_t)v[0][j], (bf16_t)v[1][j], (bf16_t)v[2][j], (bf16_t)v[3][j]};
        *reinterpret_cast<bf16x4*>(&T[nq * 4 + j][kq * 4]) = w;
    }
    __syncthreads();
    const int n = t >> 2, kc = t & 3;
    bf16x8 o0 = *reinterpret_cast<const bf16x8*>(&T[n][kc * 16]);
    bf16x8 o1 = *reinterpret_cast<const bf16x8*>(&T[n][kc * 16 + 8]);
    *reinterpret_cast<bf16x8*>(Tb + (size_t)n * KDIM + kc * 16) = o0;
    *reinterpret_cast<bf16x8*>(Tb + (size_t)n * KDIM + kc * 16 + 8) = o1;
}

// ------- Pass 2: 256x256 GEMM, 1 barrier/K-tile, counted vmcnt ring -----
// 8 waves (2M x 4N), BK=32, 4-deep K-tile LDS ring (4 x 32KB = 128KB).
// Per K-tile j: vmcnt(8) [own stage(j) landed] -> s_barrier [ALL waves'
// stage(j) landed: cross-wave guarantee] -> STAGE(j+3) [4 gl_lds into
// buf (j-1)&3, WAR-safe: its readers consumed data before the barrier]
// -> 12 ds_read_b128 (frags of buf j&3) -> 32 MFMA. vmcnt never drains
// to 0 in the main loop (T4); epilogue peels 8/8/4/0.
// LDS per buffer per matrix: [rowOct][kQ][16 rows][16B] - DMA-linear
// (byte(lane)=lane*16), fragment reads 256B-contiguous (0-conflict).
#define VM8 asm volatile("s_waitcnt vmcnt(8)" ::: "memory")
#define VM4 asm volatile("s_waitcnt vmcnt(4)" ::: "memory")
#define VM0 asm volatile("s_waitcnt vmcnt(0)" ::: "memory")
#define NOOP ((void)0)

__global__ __launch_bounds__(512, 2)
void bgemm_ring(const bf16_t* __restrict__ A, const bf16_t* __restrict__ Bt,
                float* __restrict__ O) {
    __shared__ alignas(16) bf16_t lds[65536];   // 128 KiB

    const int tid = threadIdx.x;
    const int gid = blockIdx.x;
    const int batch = gid & 7;          // one batch per XCD
    const int t = gid >> 3;
    const int bm = (t >> 3) * 256;
    const int bn = (t & 7) * 256;

    const int lane = tid & 63;
    const int wid = tid >> 6;           // 0..7
    const int wr = wid >> 2;            // 0..1 (128-row half)
    const int wc = wid & 3;             // 0..3 (64-col quarter)
    const int lr = lane & 15;
    const int lq = lane >> 4;

    const bf16_t* Ab = A + (size_t)batch * SDIM * KDIM;
    const bf16_t* Bb = Bt + (size_t)batch * NDIM * KDIM;
    float* Ob = O + (size_t)batch * SDIM * NDIM;

    // staging sources: wave w covers rows w*32..w*32+31 (2 insts of 16 rows)
    const bf16_t* aSrc0 = Ab + (size_t)(bm + wid * 32 + lr) * KDIM + lq * 8;
    const bf16_t* aSrc1 = aSrc0 + (size_t)16 * KDIM;
    const bf16_t* bSrc0 = Bb + (size_t)(bn + wid * 32 + lr) * KDIM + lq * 8;
    const bf16_t* bSrc1 = bSrc0 + (size_t)16 * KDIM;

    const int aDst0 = (wid * 2) * 512;       // LDS elem offset of rowOct 2w
    const int aDst1 = (wid * 2 + 1) * 512;
    const int rdA = lq * 128 + lr * 8;       // + (wr*8+m)*512 + buf*16384
    const int rdB = 8192 + lq * 128 + lr * 8;

#define STAGE(BUF_, KT_) do { \
    gl_lds16(aSrc0 + (size_t)(KT_) * 32, &lds[(BUF_) * 16384 + aDst0]); \
    gl_lds16(aSrc1 + (size_t)(KT_) * 32, &lds[(BUF_) * 16384 + aDst1]); \
    gl_lds16(bSrc0 + (size_t)(KT_) * 32, &lds[(BUF_) * 16384 + 8192 + aDst0]); \
    gl_lds16(bSrc1 + (size_t)(KT_) * 32, &lds[(BUF_) * 16384 + 8192 + aDst1]); \
} while (0)

    f32x4 acc[8][4];
#pragma unroll
    for (int m = 0; m < 8; ++m)
#pragma unroll
        for (int n = 0; n < 4; ++n)
            acc[m][n] = (f32x4){0.f, 0.f, 0.f, 0.f};

#define BODY(BUF_, STAGE_STMT, VM_STMT) do { \
    VM_STMT; \
    __builtin_amdgcn_s_barrier(); \
    STAGE_STMT; \
    bf16x8 af_[8], bf_[4]; \
    _Pragma("unroll") \
    for (int m_ = 0; m_ < 8; ++m_) \
        af_[m_] = *reinterpret_cast<const bf16x8*>( \
            &lds[(BUF_) * 16384 + (wr * 8 + m_) * 512 + rdA]); \
    _Pragma("unroll") \
    for (int n_ = 0; n_ < 4; ++n_) \
        bf_[n_] = *reinterpret_cast<const bf16x8*>( \
            &lds[(BUF_) * 16384 + (wc * 4 + n_) * 512 + rdB]); \
    __builtin_amdgcn_s_setprio(1); \
    _Pragma("unroll") \
    for (int m_ = 0; m_ < 8; ++m_) \
        _Pragma("unroll") \
        for (int n_ = 0; n_ < 4; ++n_) \
            acc[m_][n_] = __builtin_amdgcn_mfma_f32_16x16x32_bf16( \
                af_[m_], bf_[n_], acc[m_][n_], 0, 0, 0); \
    __builtin_amdgcn_s_setprio(0); \
} while (0)

    // prologue: stages for KT 0,1,2 in flight (12 loads)
    STAGE(0, 0);
    STAGE(1, 1);
    STAGE(2, 2);

#pragma unroll 1
    for (int j4 = 0; j4 < 60; j4 += 4) {      // j = 0..59, stages 3..62
        BODY(0, STAGE(3, j4 + 3), VM8);
        BODY(1, STAGE(0, j4 + 4), VM8);
        BODY(2, STAGE(1, j4 + 5), VM8);
        BODY(3, STAGE(2, j4 + 6), VM8);
    }
    BODY(0, STAGE(3, 63), VM8);               // j=60
    BODY(1, NOOP, VM8);                       // j=61 (12 outstanding -> 61 lands)
    BODY(2, NOOP, VM4);                       // j=62
    BODY(3, NOOP, VM0);                       // j=63

    // epilogue: C/D layout col=lane&15, row=(lane>>4)*4+reg (R1-verified)
#pragma unroll
    for (int m = 0; m < 8; ++m) {
        const int row0 = bm + wr * 128 + m * 16 + lq * 4;
#pragma unroll
        for (int n = 0; n < 4; ++n) {
            const int col = bn + wc * 64 + n * 16 + lr;
#pragma unroll
            for (int j = 0; j < 4; ++j)
                Ob[(size_t)(row0 + j) * NDIM + col] = acc[m][n][j];
        }
    }
#undef BODY
#undef STAGE
}

// ---------------- Fallback: R1 fused kernel (proven) --------------------
__device__ __forceinline__ unsigned short f2bf(float f) {
    unsigned int u = __builtin_bit_cast(unsigned int, f);
    u += 0x7fffu + ((u >> 16) & 1u);
    return (unsigned short)(u >> 16);
}

__global__ __launch_bounds__(256, 2)
void bgemm_fused(const float* __restrict__ A, const float* __restrict__ B,
                 float* __restrict__ O) {
    __shared__ alignas(16) unsigned short Asl[2][4 * 128 * 8];
    __shared__ alignas(16) unsigned short Bsl[2][4 * 128 * 8];
    const int tid = threadIdx.x;
    const int gid = blockIdx.x;
    const int batch = gid & 7;
    const int t = gid >> 3;
    const int bm = (t >> 4) * 128;
    const int bn = (t & 15) * 128;
    const float* Ab = A + (size_t)batch * SDIM * KDIM;
    const float* Bb = B + (size_t)batch * KDIM * NDIM;
    float* Ob = O + (size_t)batch * SDIM * NDIM;
    const int lane = tid & 63;
    const int wid = tid >> 6;
    const int wr = wid >> 1, wc = wid & 1;
    const int lr = lane & 15, lq = lane >> 4;
    const int r0 = tid & 127, h0 = tid >> 7;
    u16x8 areg[2], breg[2];
    f32x4 acc[4][4];
#pragma unroll
    for (int m = 0; m < 4; ++m)
#pragma unroll
        for (int n = 0; n < 4; ++n) acc[m][n] = (f32x4){0.f, 0.f, 0.f, 0.f};
    auto stage_regs = [&](int kt) {
        const int k0 = kt * 32;
        const float* ap = Ab + (size_t)(bm + r0) * KDIM + k0 + h0 * 16;
        float4 a0 = *reinterpret_cast<const float4*>(ap + 0);
        float4 a1 = *reinterpret_cast<const float4*>(ap + 4);
        float4 a2 = *reinterpret_cast<const float4*>(ap + 8);
        float4 a3 = *reinterpret_cast<const float4*>(ap + 12);
        u16x8 u;
        u[0]=f2bf(a0.x);u[1]=f2bf(a0.y);u[2]=f2bf(a0.z);u[3]=f2bf(a0.w);
        u[4]=f2bf(a1.x);u[5]=f2bf(a1.y);u[6]=f2bf(a1.z);u[7]=f2bf(a1.w);
        areg[0]=u;
        u[0]=f2bf(a2.x);u[1]=f2bf(a2.y);u[2]=f2bf(a2.z);u[3]=f2bf(a2.w);
        u[4]=f2bf(a3.x);u[5]=f2bf(a3.y);u[6]=f2bf(a3.z);u[7]=f2bf(a3.w);
        areg[1]=u;
        const float* bp = Bb + (size_t)(k0 + h0 * 16) * NDIM + bn + r0;
        float f[16];
#pragma unroll
        for (int j = 0; j < 16; ++j) f[j] = bp[(size_t)j * NDIM];
        u16x8 v;
#pragma unroll
        for (int j = 0; j < 8; ++j) v[j] = f2bf(f[j]);
        breg[0] = v;
#pragma unroll
        for (int j = 0; j < 8; ++j) v[j] = f2bf(f[8 + j]);
        breg[1] = v;
    };
    auto regs_to_lds = [&](int b) {
#pragma unroll
        for (int o = 0; o < 2; ++o) {
            *reinterpret_cast<u16x8*>(&Asl[b][((h0*2+o)*128 + r0)*8]) = areg[o];
            *reinterpret_cast<u16x8*>(&Bsl[b][((h0*2+o)*128 + r0)*8]) = breg[o];
        }
    };
    stage_regs(0);
    regs_to_lds(0);
    int buf = 0;
    for (int kt = 0; kt < KDIM / 32; ++kt) {
        if (kt + 1 < KDIM / 32) stage_regs(kt + 1);
        __syncthreads();
        bf16x8 af[4], bfv[4];
#pragma unroll
        for (int m = 0; m < 4; ++m)
            af[m] = *reinterpret_cast<const bf16x8*>(&Asl[buf][(lq*128 + wr*64 + m*16 + lr)*8]);
#pragma unroll
        for (int n = 0; n < 4; ++n)
            bfv[n] = *reinterpret_cast<const bf16x8*>(&Bsl[buf][(lq*128 + wc*64 + n*16 + lr)*8]);
#pragma unroll
        for (int m = 0; m < 4; ++m)
#pragma unroll
            for (int n = 0; n < 4; ++n)
                acc[m][n] = __builtin_amdgcn_mfma_f32_16x16x32_bf16(af[m], bfv[n], acc[m][n], 0, 0, 0);
        if (kt + 1 < KDIM / 32) regs_to_lds(buf ^ 1);
        buf ^= 1;
    }
#pragma unroll
    for (int m = 0; m < 4; ++m) {
        const int row0 = bm + wr * 64 + m * 16 + lq * 4;
#pragma unroll
        for (int n = 0; n < 4; ++n) {
            const int col = bn + wc * 64 + n * 16 + lr;
#pragma unroll
            for (int j = 0; j < 4; ++j)
                Ob[(size_t)(row0 + j) * NDIM + col] = acc[m][n][j];
        }
    }
}

extern "C" void kernel_launch(void* const* d_in, const int* in_sizes, int n_in,
                              void* d_out, int out_size, void* d_ws, size_t ws_size,
                              hipStream_t stream) {
    const float* a = (const float*)d_in[0];
    const float* b = (const float*)d_in[1];
    float* o = (float*)d_out;
    const size_t half = (size_t)BATCH * SDIM * KDIM * sizeof(bf16_t);  // 64 MiB
    if (ws_size >= 2 * half) {
        bf16_t* Abf = (bf16_t*)d_ws;
        bf16_t* Bt = (bf16_t*)((char*)d_ws + half);
        hipLaunchKernelGGL(cvtA_kernel, dim3(4096), dim3(256), 0, stream, a, Abf);
        hipLaunchKernelGGL(cvtBT_kernel, dim3(8192), dim3(256), 0, stream, b, Bt);
        hipLaunchKernelGGL(bgemm_ring, dim3(512), dim3(512), 0, stream, Abf, Bt, o);
    } else {
        hipLaunchKernelGGL(bgemm_fused, dim3(2048), dim3(256), 0, stream, a, b, o);
    }
}

// Round 7
// 254.047 us; speedup vs baseline: 1.0001x; 1.0001x over previous
//
#include <hip/hip_runtime.h>

#define BATCH 8
#define SDIM 2048
#define KDIM 2048
#define NDIM 2048

typedef __bf16 bf16_t;
typedef bf16_t bf16x4 __attribute__((ext_vector_type(4)));
typedef bf16_t bf16x8 __attribute__((ext_vector_type(8)));
typedef float f32x4 __attribute__((ext_vector_type(4)));
typedef float f32x8 __attribute__((ext_vector_type(8)));
typedef unsigned short u16x8 __attribute__((ext_vector_type(8)));

__device__ __forceinline__ void gl_lds16(const void* g, void* l) {
    // async global->LDS DMA, 16B/lane; LDS dest = wave-uniform base + lane*16
    __builtin_amdgcn_global_load_lds(
        (__attribute__((address_space(1))) void*)g,
        (__attribute__((address_space(3))) void*)l,
        16, 0, 0);
}

// ---------------- Pass 1a: A fp32 -> bf16 (elementwise) ----------------
__global__ __launch_bounds__(256)
void cvtA_kernel(const float* __restrict__ A, bf16_t* __restrict__ Abf) {
    const size_t total8 = (size_t)BATCH * SDIM * KDIM / 8;
    const size_t stride = (size_t)gridDim.x * 256;
    for (size_t i = (size_t)blockIdx.x * 256 + threadIdx.x; i < total8; i += stride) {
        f32x8 v = *reinterpret_cast<const f32x8*>(A + i * 8);
        *reinterpret_cast<bf16x8*>(Abf + i * 8) = __builtin_convertvector(v, bf16x8);
    }
}

// ------------- Pass 1b: B fp32 [K][N] -> bf16 B^T [N][K] ----------------
__global__ __launch_bounds__(256)
void cvtBT_kernel(const float* __restrict__ B, bf16_t* __restrict__ Bt) {
    __shared__ alignas(16) bf16_t T[64][72];
    const int gid = blockIdx.x;
    const int batch = gid & 7;
    const int tile = gid >> 3;
    const int k0g = (tile >> 5) * 64;
    const int n0g = (tile & 31) * 64;
    const float* Bb = B + (size_t)batch * KDIM * NDIM + (size_t)k0g * NDIM + n0g;
    bf16_t* Tb = Bt + (size_t)batch * NDIM * KDIM + (size_t)n0g * KDIM + k0g;

    const int t = threadIdx.x;
    const int kq = t & 15;
    const int nq = t >> 4;
    f32x4 v[4];
#pragma unroll
    for (int r = 0; r < 4; ++r)
        v[r] = *reinterpret_cast<const f32x4*>(Bb + (size_t)(kq * 4 + r) * NDIM + nq * 4);
#pragma unroll
    for (int j = 0; j < 4; ++j) {
        bf16x4 w = {(bf16_t)v[0][j], (bf16_t)v[1][j], (bf16_t)v[2][j], (bf16_t)v[3][j]};
        *reinterpret_cast<bf16x4*>(&T[nq * 4 + j][kq * 4]) = w;
    }
    __syncthreads();
    const int n = t >> 2, kc = t & 3;
    bf16x8 o0 = *reinterpret_cast<const bf16x8*>(&T[n][kc * 16]);
    bf16x8 o1 = *reinterpret_cast<const bf16x8*>(&T[n][kc * 16 + 8]);
    *reinterpret_cast<bf16x8*>(Tb + (size_t)n * KDIM + kc * 16) = o0;
    *reinterpret_cast<bf16x8*>(Tb + (size_t)n * KDIM + kc * 16 + 8) = o1;
}

// ------- Pass 2: 256x256 GEMM, 1 barrier/K-tile, counted vmcnt ring -----
// 8 waves (2M x 4N), BK=32, 4-deep K-tile LDS ring (4 x 32KB = 128KB).
// Per K-tile j: vmcnt(8) [own stage(j) landed] -> s_barrier [ALL waves'
// stage(j) landed: cross-wave guarantee] -> STAGE(j+3) [4 gl_lds into
// buf (j-1)&3, WAR-safe: its readers consumed data before the barrier]
// -> 12 ds_read_b128 (frags of buf j&3) -> 32 MFMA. vmcnt never drains
// to 0 in the main loop (T4); epilogue peels 8/8/4/0.
// LDS per buffer per matrix: [rowOct][kQ][16 rows][16B] - DMA-linear
// (byte(lane)=lane*16), fragment reads 256B-contiguous (0-conflict).
#define VM8 asm volatile("s_waitcnt vmcnt(8)" ::: "memory")
#define VM4 asm volatile("s_waitcnt vmcnt(4)" ::: "memory")
#define VM0 asm volatile("s_waitcnt vmcnt(0)" ::: "memory")
#define NOOP ((void)0)

__global__ __launch_bounds__(512, 2)
void bgemm_ring(const bf16_t* __restrict__ A, const bf16_t* __restrict__ Bt,
                float* __restrict__ O) {
    __shared__ alignas(16) bf16_t lds[65536];   // 128 KiB

    const int tid = threadIdx.x;
    const int gid = blockIdx.x;
    const int batch = gid & 7;          // one batch per XCD
    const int t = gid >> 3;
    const int bm = (t >> 3) * 256;
    const int bn = (t & 7) * 256;

    const int lane = tid & 63;
    const int wid = tid >> 6;           // 0..7
    const int wr = wid >> 2;            // 0..1 (128-row half)
    const int wc = wid & 3;             // 0..3 (64-col quarter)
    const int lr = lane & 15;
    const int lq = lane >> 4;

    const bf16_t* Ab = A + (size_t)batch * SDIM * KDIM;
    const bf16_t* Bb = Bt + (size_t)batch * NDIM * KDIM;
    float* Ob = O + (size_t)batch * SDIM * NDIM;

    // staging sources: wave w covers rows w*32..w*32+31 (2 insts of 16 rows)
    const bf16_t* aSrc0 = Ab + (size_t)(bm + wid * 32 + lr) * KDIM + lq * 8;
    const bf16_t* aSrc1 = aSrc0 + (size_t)16 * KDIM;
    const bf16_t* bSrc0 = Bb + (size_t)(bn + wid * 32 + lr) * KDIM + lq * 8;
    const bf16_t* bSrc1 = bSrc0 + (size_t)16 * KDIM;

    const int aDst0 = (wid * 2) * 512;       // LDS elem offset of rowOct 2w
    const int aDst1 = (wid * 2 + 1) * 512;
    const int rdA = lq * 128 + lr * 8;       // + (wr*8+m)*512 + buf*16384
    const int rdB = 8192 + lq * 128 + lr * 8;

#define STAGE(BUF_, KT_) do { \
    gl_lds16(aSrc0 + (size_t)(KT_) * 32, &lds[(BUF_) * 16384 + aDst0]); \
    gl_lds16(aSrc1 + (size_t)(KT_) * 32, &lds[(BUF_) * 16384 + aDst1]); \
    gl_lds16(bSrc0 + (size_t)(KT_) * 32, &lds[(BUF_) * 16384 + 8192 + aDst0]); \
    gl_lds16(bSrc1 + (size_t)(KT_) * 32, &lds[(BUF_) * 16384 + 8192 + aDst1]); \
} while (0)

    f32x4 acc[8][4];
#pragma unroll
    for (int m = 0; m < 8; ++m)
#pragma unroll
        for (int n = 0; n < 4; ++n)
            acc[m][n] = (f32x4){0.f, 0.f, 0.f, 0.f};

#define BODY(BUF_, STAGE_STMT, VM_STMT) do { \
    VM_STMT; \
    __builtin_amdgcn_s_barrier(); \
    STAGE_STMT; \
    bf16x8 af_[8], bf_[4]; \
    _Pragma("unroll") \
    for (int m_ = 0; m_ < 8; ++m_) \
        af_[m_] = *reinterpret_cast<const bf16x8*>( \
            &lds[(BUF_) * 16384 + (wr * 8 + m_) * 512 + rdA]); \
    _Pragma("unroll") \
    for (int n_ = 0; n_ < 4; ++n_) \
        bf_[n_] = *reinterpret_cast<const bf16x8*>( \
            &lds[(BUF_) * 16384 + (wc * 4 + n_) * 512 + rdB]); \
    __builtin_amdgcn_s_setprio(1); \
    _Pragma("unroll") \
    for (int m_ = 0; m_ < 8; ++m_) \
        _Pragma("unroll") \
        for (int n_ = 0; n_ < 4; ++n_) \
            acc[m_][n_] = __builtin_amdgcn_mfma_f32_16x16x32_bf16( \
                af_[m_], bf_[n_], acc[m_][n_], 0, 0, 0); \
    __builtin_amdgcn_s_setprio(0); \
} while (0)

    // prologue: stages for KT 0,1,2 in flight (12 loads)
    STAGE(0, 0);
    STAGE(1, 1);
    STAGE(2, 2);

#pragma unroll 1
    for (int j4 = 0; j4 < 60; j4 += 4) {      // j = 0..59, stages 3..62
        BODY(0, STAGE(3, j4 + 3), VM8);
        BODY(1, STAGE(0, j4 + 4), VM8);
        BODY(2, STAGE(1, j4 + 5), VM8);
        BODY(3, STAGE(2, j4 + 6), VM8);
    }
    BODY(0, STAGE(3, 63), VM8);               // j=60
    BODY(1, NOOP, VM8);                       // j=61 (12 outstanding -> 61 lands)
    BODY(2, NOOP, VM4);                       // j=62
    BODY(3, NOOP, VM0);                       // j=63

    // epilogue: C/D layout col=lane&15, row=(lane>>4)*4+reg (R1-verified)
#pragma unroll
    for (int m = 0; m < 8; ++m) {
        const int row0 = bm + wr * 128 + m * 16 + lq * 4;
#pragma unroll
        for (int n = 0; n < 4; ++n) {
            const int col = bn + wc * 64 + n * 16 + lr;
#pragma unroll
            for (int j = 0; j < 4; ++j)
                Ob[(size_t)(row0 + j) * NDIM + col] = acc[m][n][j];
        }
    }
#undef BODY
#undef STAGE
}

// ---------------- Fallback: R1 fused kernel (proven) --------------------
__device__ __forceinline__ unsigned short f2bf(float f) {
    unsigned int u = __builtin_bit_cast(unsigned int, f);
    u += 0x7fffu + ((u >> 16) & 1u);
    return (unsigned short)(u >> 16);
}

__global__ __launch_bounds__(256, 2)
void bgemm_fused(const float* __restrict__ A, const float* __restrict__ B,
                 float* __restrict__ O) {
    __shared__ alignas(16) unsigned short Asl[2][4 * 128 * 8];
    __shared__ alignas(16) unsigned short Bsl[2][4 * 128 * 8];
    const int tid = threadIdx.x;
    const int gid = blockIdx.x;
    const int batch = gid & 7;
    const int t = gid >> 3;
    const int bm = (t >> 4) * 128;
    const int bn = (t & 15) * 128;
    const float* Ab = A + (size_t)batch * SDIM * KDIM;
    const float* Bb = B + (size_t)batch * KDIM * NDIM;
    float* Ob = O + (size_t)batch * SDIM * NDIM;
    const int lane = tid & 63;
    const int wid = tid >> 6;
    const int wr = wid >> 1, wc = wid & 1;
    const int lr = lane & 15, lq = lane >> 4;
    const int r0 = tid & 127, h0 = tid >> 7;
    u16x8 areg[2], breg[2];
    f32x4 acc[4][4];
#pragma unroll
    for (int m = 0; m < 4; ++m)
#pragma unroll
        for (int n = 0; n < 4; ++n) acc[m][n] = (f32x4){0.f, 0.f, 0.f, 0.f};
    auto stage_regs = [&](int kt) {
        const int k0 = kt * 32;
        const float* ap = Ab + (size_t)(bm + r0) * KDIM + k0 + h0 * 16;
        float4 a0 = *reinterpret_cast<const float4*>(ap + 0);
        float4 a1 = *reinterpret_cast<const float4*>(ap + 4);
        float4 a2 = *reinterpret_cast<const float4*>(ap + 8);
        float4 a3 = *reinterpret_cast<const float4*>(ap + 12);
        u16x8 u;
        u[0]=f2bf(a0.x);u[1]=f2bf(a0.y);u[2]=f2bf(a0.z);u[3]=f2bf(a0.w);
        u[4]=f2bf(a1.x);u[5]=f2bf(a1.y);u[6]=f2bf(a1.z);u[7]=f2bf(a1.w);
        areg[0]=u;
        u[0]=f2bf(a2.x);u[1]=f2bf(a2.y);u[2]=f2bf(a2.z);u[3]=f2bf(a2.w);
        u[4]=f2bf(a3.x);u[5]=f2bf(a3.y);u[6]=f2bf(a3.z);u[7]=f2bf(a3.w);
        areg[1]=u;
        const float* bp = Bb + (size_t)(k0 + h0 * 16) * NDIM + bn + r0;
        float f[16];
#pragma unroll
        for (int j = 0; j < 16; ++j) f[j] = bp[(size_t)j * NDIM];
        u16x8 v;
#pragma unroll
        for (int j = 0; j < 8; ++j) v[j] = f2bf(f[j]);
        breg[0] = v;
#pragma unroll
        for (int j = 0; j < 8; ++j) v[j] = f2bf(f[8 + j]);
        breg[1] = v;
    };
    auto regs_to_lds = [&](int b) {
#pragma unroll
        for (int o = 0; o < 2; ++o) {
            *reinterpret_cast<u16x8*>(&Asl[b][((h0*2+o)*128 + r0)*8]) = areg[o];
            *reinterpret_cast<u16x8*>(&Bsl[b][((h0*2+o)*128 + r0)*8]) = breg[o];
        }
    };
    stage_regs(0);
    regs_to_lds(0);
    int buf = 0;
    for (int kt = 0; kt < KDIM / 32; ++kt) {
        if (kt + 1 < KDIM / 32) stage_regs(kt + 1);
        __syncthreads();
        bf16x8 af[4], bfv[4];
#pragma unroll
        for (int m = 0; m < 4; ++m)
            af[m] = *reinterpret_cast<const bf16x8*>(&Asl[buf][(lq*128 + wr*64 + m*16 + lr)*8]);
#pragma unroll
        for (int n = 0; n < 4; ++n)
            bfv[n] = *reinterpret_cast<const bf16x8*>(&Bsl[buf][(lq*128 + wc*64 + n*16 + lr)*8]);
#pragma unroll
        for (int m = 0; m < 4; ++m)
#pragma unroll
            for (int n = 0; n < 4; ++n)
                acc[m][n] = __builtin_amdgcn_mfma_f32_16x16x32_bf16(af[m], bfv[n], acc[m][n], 0, 0, 0);
        if (kt + 1 < KDIM / 32) regs_to_lds(buf ^ 1);
        buf ^= 1;
    }
#pragma unroll
    for (int m = 0; m < 4; ++m) {
        const int row0 = bm + wr * 64 + m * 16 + lq * 4;
#pragma unroll
        for (int n = 0; n < 4; ++n) {
            const int col = bn + wc * 64 + n * 16 + lr;
#pragma unroll
            for (int j = 0; j < 4; ++j)
                Ob[(size_t)(row0 + j) * NDIM + col] = acc[m][n][j];
        }
    }
}

extern "C" void kernel_launch(void* const* d_in, const int* in_sizes, int n_in,
                              void* d_out, int out_size, void* d_ws, size_t ws_size,
                              hipStream_t stream) {
    const float* a = (const float*)d_in[0];
    const float* b = (const float*)d_in[1];
    float* o = (float*)d_out;
    const size_t half = (size_t)BATCH * SDIM * KDIM * sizeof(bf16_t);  // 64 MiB
    if (ws_size >= 2 * half) {
        bf16_t* Abf = (bf16_t*)d_ws;
        bf16_t* Bt = (bf16_t*)((char*)d_ws + half);
        hipLaunchKernelGGL(cvtA_kernel, dim3(4096), dim3(256), 0, stream, a, Abf);
        hipLaunchKernelGGL(cvtBT_kernel, dim3(8192), dim3(256), 0, stream, b, Bt);
        hipLaunchKernelGGL(bgemm_ring, dim3(512), dim3(512), 0, stream, Abf, Bt, o);
    } else {
        hipLaunchKernelGGL(bgemm_fused, dim3(2048), dim3(256), 0, stream, a, b, o);
    }
}

// Round 8
// 252.542 us; speedup vs baseline: 1.0060x; 1.0060x over previous
//
#include <hip/hip_runtime.h>

#define BATCH 8
#define SDIM 2048
#define KDIM 2048
#define NDIM 2048

typedef __bf16 bf16_t;
typedef bf16_t bf16x4 __attribute__((ext_vector_type(4)));
typedef bf16_t bf16x8 __attribute__((ext_vector_type(8)));
typedef float f32x4 __attribute__((ext_vector_type(4)));
typedef float f32x8 __attribute__((ext_vector_type(8)));
typedef unsigned short u16x8 __attribute__((ext_vector_type(8)));

__device__ __forceinline__ void gl_lds16(const void* g, void* l) {
    // async global->LDS DMA, 16B/lane; LDS dest = wave-uniform base + lane*16
    __builtin_amdgcn_global_load_lds(
        (__attribute__((address_space(1))) void*)g,
        (__attribute__((address_space(3))) void*)l,
        16, 0, 0);
}

// ---------------- Pass 1a: A fp32 -> bf16 (elementwise) ----------------
__global__ __launch_bounds__(256)
void cvtA_kernel(const float* __restrict__ A, bf16_t* __restrict__ Abf) {
    const size_t total8 = (size_t)BATCH * SDIM * KDIM / 8;
    const size_t stride = (size_t)gridDim.x * 256;
    for (size_t i = (size_t)blockIdx.x * 256 + threadIdx.x; i < total8; i += stride) {
        f32x8 v = *reinterpret_cast<const f32x8*>(A + i * 8);
        *reinterpret_cast<bf16x8*>(Abf + i * 8) = __builtin_convertvector(v, bf16x8);
    }
}

// ------------- Pass 1b: B fp32 [K][N] -> bf16 B^T [N][K] ----------------
__global__ __launch_bounds__(256)
void cvtBT_kernel(const float* __restrict__ B, bf16_t* __restrict__ Bt) {
    __shared__ alignas(16) bf16_t T[64][72];
    const int gid = blockIdx.x;
    const int batch = gid & 7;
    const int tile = gid >> 3;
    const int k0g = (tile >> 5) * 64;
    const int n0g = (tile & 31) * 64;
    const float* Bb = B + (size_t)batch * KDIM * NDIM + (size_t)k0g * NDIM + n0g;
    bf16_t* Tb = Bt + (size_t)batch * NDIM * KDIM + (size_t)n0g * KDIM + k0g;

    const int t = threadIdx.x;
    const int kq = t & 15;
    const int nq = t >> 4;
    f32x4 v[4];
#pragma unroll
    for (int r = 0; r < 4; ++r)
        v[r] = *reinterpret_cast<const f32x4*>(Bb + (size_t)(kq * 4 + r) * NDIM + nq * 4);
#pragma unroll
    for (int j = 0; j < 4; ++j) {
        bf16x4 w = {(bf16_t)v[0][j], (bf16_t)v[1][j], (bf16_t)v[2][j], (bf16_t)v[3][j]};
        *reinterpret_cast<bf16x4*>(&T[nq * 4 + j][kq * 4]) = w;
    }
    __syncthreads();
    const int n = t >> 2, kc = t & 3;
    bf16x8 o0 = *reinterpret_cast<const bf16x8*>(&T[n][kc * 16]);
    bf16x8 o1 = *reinterpret_cast<const bf16x8*>(&T[n][kc * 16 + 8]);
    *reinterpret_cast<bf16x8*>(Tb + (size_t)n * KDIM + kc * 16) = o0;
    *reinterpret_cast<bf16x8*>(Tb + (size_t)n * KDIM + kc * 16 + 8) = o1;
}

// ------- Pass 2: 256x256 GEMM, 1 barrier/K-tile, counted vmcnt ring -----
// 8 waves (2M x 4N), BK=32, 4-deep K-tile LDS ring (4 x 32KB = 128KB).
// Per K-tile j: vmcnt(8) [own stage(j) landed] -> s_barrier [ALL waves'
// stage(j) landed: cross-wave guarantee] -> STAGE(j+3) [4 gl_lds into
// buf (j-1)&3, WAR-safe: its readers consumed data before the barrier]
// -> 12 ds_read_b128 (frags of buf j&3) -> 32 MFMA. vmcnt never drains
// to 0 in the main loop (T4); epilogue peels 8/8/4/0.
// LDS per buffer per matrix: [rowOct][kQ][16 rows][16B] - DMA-linear
// (byte(lane)=lane*16), fragment reads 256B-contiguous (0-conflict).
#define VM8 asm volatile("s_waitcnt vmcnt(8)" ::: "memory")
#define VM4 asm volatile("s_waitcnt vmcnt(4)" ::: "memory")
#define VM0 asm volatile("s_waitcnt vmcnt(0)" ::: "memory")
#define NOOP ((void)0)

__global__ __launch_bounds__(512, 2)
void bgemm_ring(const bf16_t* __restrict__ A, const bf16_t* __restrict__ Bt,
                float* __restrict__ O) {
    __shared__ alignas(16) bf16_t lds[65536];   // 128 KiB

    const int tid = threadIdx.x;
    const int gid = blockIdx.x;
    const int batch = gid & 7;          // one batch per XCD
    const int t = gid >> 3;
    const int bm = (t >> 3) * 256;
    const int bn = (t & 7) * 256;

    const int lane = tid & 63;
    const int wid = tid >> 6;           // 0..7
    const int wr = wid >> 2;            // 0..1 (128-row half)
    const int wc = wid & 3;             // 0..3 (64-col quarter)
    const int lr = lane & 15;
    const int lq = lane >> 4;

    const bf16_t* Ab = A + (size_t)batch * SDIM * KDIM;
    const bf16_t* Bb = Bt + (size_t)batch * NDIM * KDIM;
    float* Ob = O + (size_t)batch * SDIM * NDIM;

    // staging sources: wave w covers rows w*32..w*32+31 (2 insts of 16 rows)
    const bf16_t* aSrc0 = Ab + (size_t)(bm + wid * 32 + lr) * KDIM + lq * 8;
    const bf16_t* aSrc1 = aSrc0 + (size_t)16 * KDIM;
    const bf16_t* bSrc0 = Bb + (size_t)(bn + wid * 32 + lr) * KDIM + lq * 8;
    const bf16_t* bSrc1 = bSrc0 + (size_t)16 * KDIM;

    const int aDst0 = (wid * 2) * 512;       // LDS elem offset of rowOct 2w
    const int aDst1 = (wid * 2 + 1) * 512;
    const int rdA = lq * 128 + lr * 8;       // + (wr*8+m)*512 + buf*16384
    const int rdB = 8192 + lq * 128 + lr * 8;

#define STAGE(BUF_, KT_) do { \
    gl_lds16(aSrc0 + (size_t)(KT_) * 32, &lds[(BUF_) * 16384 + aDst0]); \
    gl_lds16(aSrc1 + (size_t)(KT_) * 32, &lds[(BUF_) * 16384 + aDst1]); \
    gl_lds16(bSrc0 + (size_t)(KT_) * 32, &lds[(BUF_) * 16384 + 8192 + aDst0]); \
    gl_lds16(bSrc1 + (size_t)(KT_) * 32, &lds[(BUF_) * 16384 + 8192 + aDst1]); \
} while (0)

    f32x4 acc[8][4];
#pragma unroll
    for (int m = 0; m < 8; ++m)
#pragma unroll
        for (int n = 0; n < 4; ++n)
            acc[m][n] = (f32x4){0.f, 0.f, 0.f, 0.f};

#define BODY(BUF_, STAGE_STMT, VM_STMT) do { \
    VM_STMT; \
    __builtin_amdgcn_s_barrier(); \
    STAGE_STMT; \
    bf16x8 af_[8], bf_[4]; \
    _Pragma("unroll") \
    for (int m_ = 0; m_ < 8; ++m_) \
        af_[m_] = *reinterpret_cast<const bf16x8*>( \
            &lds[(BUF_) * 16384 + (wr * 8 + m_) * 512 + rdA]); \
    _Pragma("unroll") \
    for (int n_ = 0; n_ < 4; ++n_) \
        bf_[n_] = *reinterpret_cast<const bf16x8*>( \
            &lds[(BUF_) * 16384 + (wc * 4 + n_) * 512 + rdB]); \
    __builtin_amdgcn_s_setprio(1); \
    _Pragma("unroll") \
    for (int m_ = 0; m_ < 8; ++m_) \
        _Pragma("unroll") \
        for (int n_ = 0; n_ < 4; ++n_) \
            acc[m_][n_] = __builtin_amdgcn_mfma_f32_16x16x32_bf16( \
                af_[m_], bf_[n_], acc[m_][n_], 0, 0, 0); \
    __builtin_amdgcn_s_setprio(0); \
} while (0)

    // prologue: stages for KT 0,1,2 in flight (12 loads)
    STAGE(0, 0);
    STAGE(1, 1);
    STAGE(2, 2);

#pragma unroll 1
    for (int j4 = 0; j4 < 60; j4 += 4) {      // j = 0..59, stages 3..62
        BODY(0, STAGE(3, j4 + 3), VM8);
        BODY(1, STAGE(0, j4 + 4), VM8);
        BODY(2, STAGE(1, j4 + 5), VM8);
        BODY(3, STAGE(2, j4 + 6), VM8);
    }
    BODY(0, STAGE(3, 63), VM8);               // j=60
    BODY(1, NOOP, VM8);                       // j=61 (12 outstanding -> 61 lands)
    BODY(2, NOOP, VM4);                       // j=62
    BODY(3, NOOP, VM0);                       // j=63

    // epilogue: C/D layout col=lane&15, row=(lane>>4)*4+reg (R1-verified)
#pragma unroll
    for (int m = 0; m < 8; ++m) {
        const int row0 = bm + wr * 128 + m * 16 + lq * 4;
#pragma unroll
        for (int n = 0; n < 4; ++n) {
            const int col = bn + wc * 64 + n * 16 + lr;
#pragma unroll
            for (int j = 0; j < 4; ++j)
                Ob[(size_t)(row0 + j) * NDIM + col] = acc[m][n][j];
        }
    }
#undef BODY
#undef STAGE
}

// ---------------- Fallback: R1 fused kernel (proven) --------------------
__device__ __forceinline__ unsigned short f2bf(float f) {
    unsigned int u = __builtin_bit_cast(unsigned int, f);
    u += 0x7fffu + ((u >> 16) & 1u);
    return (unsigned short)(u >> 16);
}

__global__ __launch_bounds__(256, 2)
void bgemm_fused(const float* __restrict__ A, const float* __restrict__ B,
                 float* __restrict__ O) {
    __shared__ alignas(16) unsigned short Asl[2][4 * 128 * 8];
    __shared__ alignas(16) unsigned short Bsl[2][4 * 128 * 8];
    const int tid = threadIdx.x;
    const int gid = blockIdx.x;
    const int batch = gid & 7;
    const int t = gid >> 3;
    const int bm = (t >> 4) * 128;
    const int bn = (t & 15) * 128;
    const float* Ab = A + (size_t)batch * SDIM * KDIM;
    const float* Bb = B + (size_t)batch * KDIM * NDIM;
    float* Ob = O + (size_t)batch * SDIM * NDIM;
    const int lane = tid & 63;
    const int wid = tid >> 6;
    const int wr = wid >> 1, wc = wid & 1;
    const int lr = lane & 15, lq = lane >> 4;
    const int r0 = tid & 127, h0 = tid >> 7;
    u16x8 areg[2], breg[2];
    f32x4 acc[4][4];
#pragma unroll
    for (int m = 0; m < 4; ++m)
#pragma unroll
        for (int n = 0; n < 4; ++n) acc[m][n] = (f32x4){0.f, 0.f, 0.f, 0.f};
    auto stage_regs = [&](int kt) {
        const int k0 = kt * 32;
        const float* ap = Ab + (size_t)(bm + r0) * KDIM + k0 + h0 * 16;
        float4 a0 = *reinterpret_cast<const float4*>(ap + 0);
        float4 a1 = *reinterpret_cast<const float4*>(ap + 4);
        float4 a2 = *reinterpret_cast<const float4*>(ap + 8);
        float4 a3 = *reinterpret_cast<const float4*>(ap + 12);
        u16x8 u;
        u[0]=f2bf(a0.x);u[1]=f2bf(a0.y);u[2]=f2bf(a0.z);u[3]=f2bf(a0.w);
        u[4]=f2bf(a1.x);u[5]=f2bf(a1.y);u[6]=f2bf(a1.z);u[7]=f2bf(a1.w);
        areg[0]=u;
        u[0]=f2bf(a2.x);u[1]=f2bf(a2.y);u[2]=f2bf(a2.z);u[3]=f2bf(a2.w);
        u[4]=f2bf(a3.x);u[5]=f2bf(a3.y);u[6]=f2bf(a3.z);u[7]=f2bf(a3.w);
        areg[1]=u;
        const float* bp = Bb + (size_t)(k0 + h0 * 16) * NDIM + bn + r0;
        float f[16];
#pragma unroll
        for (int j = 0; j < 16; ++j) f[j] = bp[(size_t)j * NDIM];
        u16x8 v;
#pragma unroll
        for (int j = 0; j < 8; ++j) v[j] = f2bf(f[j]);
        breg[0] = v;
#pragma unroll
        for (int j = 0; j < 8; ++j) v[j] = f2bf(f[8 + j]);
        breg[1] = v;
    };
    auto regs_to_lds = [&](int b) {
#pragma unroll
        for (int o = 0; o < 2; ++o) {
            *reinterpret_cast<u16x8*>(&Asl[b][((h0*2+o)*128 + r0)*8]) = areg[o];
            *reinterpret_cast<u16x8*>(&Bsl[b][((h0*2+o)*128 + r0)*8]) = breg[o];
        }
    };
    stage_regs(0);
    regs_to_lds(0);
    int buf = 0;
    for (int kt = 0; kt < KDIM / 32; ++kt) {
        if (kt + 1 < KDIM / 32) stage_regs(kt + 1);
        __syncthreads();
        bf16x8 af[4], bfv[4];
#pragma unroll
        for (int m = 0; m < 4; ++m)
            af[m] = *reinterpret_cast<const bf16x8*>(&Asl[buf][(lq*128 + wr*64 + m*16 + lr)*8]);
#pragma unroll
        for (int n = 0; n < 4; ++n)
            bfv[n] = *reinterpret_cast<const bf16x8*>(&Bsl[buf][(lq*128 + wc*64 + n*16 + lr)*8]);
#pragma unroll
        for (int m = 0; m < 4; ++m)
#pragma unroll
            for (int n = 0; n < 4; ++n)
                acc[m][n] = __builtin_amdgcn_mfma_f32_16x16x32_bf16(af[m], bfv[n], acc[m][n], 0, 0, 0);
        if (kt + 1 < KDIM / 32) regs_to_lds(buf ^ 1);
        buf ^= 1;
    }
#pragma unroll
    for (int m = 0; m < 4; ++m) {
        const int row0 = bm + wr * 64 + m * 16 + lq * 4;
#pragma unroll
        for (int n = 0; n < 4; ++n) {
            const int col = bn + wc * 64 + n * 16 + lr;
#pragma unroll
            for (int j = 0; j < 4; ++j)
                Ob[(size_t)(row0 + j) * NDIM + col] = acc[m][n][j];
        }
    }
}

extern "C" void kernel_launch(void* const* d_in, const int* in_sizes, int n_in,
                              void* d_out, int out_size, void* d_ws, size_t ws_size,
                              hipStream_t stream) {
    const float* a = (const float*)d_in[0];
    const float* b = (const float*)d_in[1];
    float* o = (float*)d_out;
    const size_t half = (size_t)BATCH * SDIM * KDIM * sizeof(bf16_t);  // 64 MiB
    if (ws_size >= 2 * half) {
        bf16_t* Abf = (bf16_t*)d_ws;
        bf16_t* Bt = (bf16_t*)((char*)d_ws + half);
        hipLaunchKernelGGL(cvtA_kernel, dim3(4096), dim3(256), 0, stream, a, Abf);
        hipLaunchKernelGGL(cvtBT_kernel, dim3(8192), dim3(256), 0, stream, b, Bt);
        hipLaunchKernelGGL(bgemm_ring, dim3(512), dim3(512), 0, stream, Abf, Bt, o);
    } else {
        hipLaunchKernelGGL(bgemm_fused, dim3(2048), dim3(256), 0, stream, a, b, o);
    }
}

// Round 9
// 251.456 us; speedup vs baseline: 1.0104x; 1.0043x over previous
//
#include <hip/hip_runtime.h>

#define BATCH 8
#define SDIM 2048
#define KDIM 2048
#define NDIM 2048

typedef __bf16 bf16_t;
typedef bf16_t bf16x4 __attribute__((ext_vector_type(4)));
typedef bf16_t bf16x8 __attribute__((ext_vector_type(8)));
typedef float f32x4 __attribute__((ext_vector_type(4)));
typedef float f32x8 __attribute__((ext_vector_type(8)));
typedef unsigned short u16x8 __attribute__((ext_vector_type(8)));

__device__ __forceinline__ void gl_lds16(const void* g, void* l) {
    // async global->LDS DMA, 16B/lane; LDS dest = wave-uniform base + lane*16
    __builtin_amdgcn_global_load_lds(
        (__attribute__((address_space(1))) void*)g,
        (__attribute__((address_space(3))) void*)l,
        16, 0, 0);
}

// ---------------- Pass 1a: A fp32 -> bf16 (elementwise) ----------------
__global__ __launch_bounds__(256)
void cvtA_kernel(const float* __restrict__ A, bf16_t* __restrict__ Abf) {
    const size_t total8 = (size_t)BATCH * SDIM * KDIM / 8;
    const size_t stride = (size_t)gridDim.x * 256;
    for (size_t i = (size_t)blockIdx.x * 256 + threadIdx.x; i < total8; i += stride) {
        f32x8 v = *reinterpret_cast<const f32x8*>(A + i * 8);
        *reinterpret_cast<bf16x8*>(Abf + i * 8) = __builtin_convertvector(v, bf16x8);
    }
}

// ------------- Pass 1b: B fp32 [K][N] -> bf16 B^T [N][K] ----------------
__global__ __launch_bounds__(256)
void cvtBT_kernel(const float* __restrict__ B, bf16_t* __restrict__ Bt) {
    __shared__ alignas(16) bf16_t T[64][72];
    const int gid = blockIdx.x;
    const int batch = gid & 7;
    const int tile = gid >> 3;
    const int k0g = (tile >> 5) * 64;
    const int n0g = (tile & 31) * 64;
    const float* Bb = B + (size_t)batch * KDIM * NDIM + (size_t)k0g * NDIM + n0g;
    bf16_t* Tb = Bt + (size_t)batch * NDIM * KDIM + (size_t)n0g * KDIM + k0g;

    const int t = threadIdx.x;
    const int kq = t & 15;
    const int nq = t >> 4;
    f32x4 v[4];
#pragma unroll
    for (int r = 0; r < 4; ++r)
        v[r] = *reinterpret_cast<const f32x4*>(Bb + (size_t)(kq * 4 + r) * NDIM + nq * 4);
#pragma unroll
    for (int j = 0; j < 4; ++j) {
        bf16x4 w = {(bf16_t)v[0][j], (bf16_t)v[1][j], (bf16_t)v[2][j], (bf16_t)v[3][j]};
        *reinterpret_cast<bf16x4*>(&T[nq * 4 + j][kq * 4]) = w;
    }
    __syncthreads();
    const int n = t >> 2, kc = t & 3;
    bf16x8 o0 = *reinterpret_cast<const bf16x8*>(&T[n][kc * 16]);
    bf16x8 o1 = *reinterpret_cast<const bf16x8*>(&T[n][kc * 16 + 8]);
    *reinterpret_cast<bf16x8*>(Tb + (size_t)n * KDIM + kc * 16) = o0;
    *reinterpret_cast<bf16x8*>(Tb + (size_t)n * KDIM + kc * 16 + 8) = o1;
}

// -- Pass 2: 256x256 GEMM, 1 barrier/K-tile, straddled MFMA/read pipeline --
// 8 waves (2M x 4N), BK=32, 4-deep K-tile LDS ring (4 x 32KB = 128KB),
// prefetch depth 2 (stage j+2 at region j -> overwrites tile j-2: its last
// reads (A-hi(j-2)) were consumed by MFMA_HI at top of region j-1, before
// the barrier that precedes this stage => WAR-safe).
// Region j (between barriers): MFMA_HI(j-1) [indep of reads] ->
// read A-lo(j)+B(j) [8 ds_read, overlap HI drain] -> STAGE(j+2) ->
// read A-hi(j) [4] -> MFMA_LO(j) [lgkm covered by issue distance] ->
// vmcnt(4) [stage(j+1) landed, stage(j+2) stays in flight] -> barrier.
// MFMA_HI(j) runs AFTER the barrier, overlapping region j+1's reads.
#define VM4 asm volatile("s_waitcnt vmcnt(4)" ::: "memory")
#define VM0 asm volatile("s_waitcnt vmcnt(0)" ::: "memory")
#define NOOP ((void)0)

__global__ __launch_bounds__(512, 2)
void bgemm_pipe(const bf16_t* __restrict__ A, const bf16_t* __restrict__ Bt,
                float* __restrict__ O) {
    __shared__ alignas(16) bf16_t lds[65536];   // 4 x 32KB = 128 KiB

    const int tid = threadIdx.x;
    const int gid = blockIdx.x;
    const int batch = gid & 7;          // one batch per XCD
    const int t = gid >> 3;
    const int bm = (t >> 3) * 256;
    const int bn = (t & 7) * 256;

    const int lane = tid & 63;
    const int wid = tid >> 6;           // 0..7
    const int wr = wid >> 2;            // 0..1 (128-row half)
    const int wc = wid & 3;             // 0..3 (64-col quarter)
    const int lr = lane & 15;
    const int lq = lane >> 4;

    const bf16_t* Ab = A + (size_t)batch * SDIM * KDIM;
    const bf16_t* Bb = Bt + (size_t)batch * NDIM * KDIM;
    float* Ob = O + (size_t)batch * SDIM * NDIM;

    // staging sources: wave w covers rows w*32..w*32+31 (2 insts of 16 rows)
    const bf16_t* aSrc0 = Ab + (size_t)(bm + wid * 32 + lr) * KDIM + lq * 8;
    const bf16_t* aSrc1 = aSrc0 + (size_t)16 * KDIM;
    const bf16_t* bSrc0 = Bb + (size_t)(bn + wid * 32 + lr) * KDIM + lq * 8;
    const bf16_t* bSrc1 = bSrc0 + (size_t)16 * KDIM;

    const int aDst0 = (wid * 2) * 512;       // LDS elem offset of rowOct 2w
    const int aDst1 = (wid * 2 + 1) * 512;
    const int rdA = lq * 128 + lr * 8;       // + (wr*8+m)*512 + buf*16384
    const int rdB = 8192 + lq * 128 + lr * 8;

#define STAGE(BUF_, KT_) do { \
    gl_lds16(aSrc0 + (size_t)(KT_) * 32, &lds[(BUF_) * 16384 + aDst0]); \
    gl_lds16(aSrc1 + (size_t)(KT_) * 32, &lds[(BUF_) * 16384 + aDst1]); \
    gl_lds16(bSrc0 + (size_t)(KT_) * 32, &lds[(BUF_) * 16384 + 8192 + aDst0]); \
    gl_lds16(bSrc1 + (size_t)(KT_) * 32, &lds[(BUF_) * 16384 + 8192 + aDst1]); \
} while (0)

    f32x4 acc[8][4];
#pragma unroll
    for (int m = 0; m < 8; ++m)
#pragma unroll
        for (int n = 0; n < 4; ++n)
            acc[m][n] = (f32x4){0.f, 0.f, 0.f, 0.f};

    bf16x8 aLo[4], aHi[4], bFr[4];

#define READ_LOB(BUF_) do { \
    _Pragma("unroll") \
    for (int m_ = 0; m_ < 4; ++m_) \
        aLo[m_] = *reinterpret_cast<const bf16x8*>( \
            &lds[(BUF_) * 16384 + (wr * 8 + m_) * 512 + rdA]); \
    _Pragma("unroll") \
    for (int n_ = 0; n_ < 4; ++n_) \
        bFr[n_] = *reinterpret_cast<const bf16x8*>( \
            &lds[(BUF_) * 16384 + (wc * 4 + n_) * 512 + rdB]); \
} while (0)

#define READ_HI(BUF_) do { \
    _Pragma("unroll") \
    for (int m_ = 0; m_ < 4; ++m_) \
        aHi[m_] = *reinterpret_cast<const bf16x8*>( \
            &lds[(BUF_) * 16384 + (wr * 8 + 4 + m_) * 512 + rdA]); \
} while (0)

#define MFMA_LO do { \
    __builtin_amdgcn_s_setprio(1); \
    _Pragma("unroll") \
    for (int m_ = 0; m_ < 4; ++m_) \
        _Pragma("unroll") \
        for (int n_ = 0; n_ < 4; ++n_) \
            acc[m_][n_] = __builtin_amdgcn_mfma_f32_16x16x32_bf16( \
                aLo[m_], bFr[n_], acc[m_][n_], 0, 0, 0); \
    __builtin_amdgcn_s_setprio(0); \
} while (0)

#define MFMA_HI do { \
    __builtin_amdgcn_s_setprio(1); \
    _Pragma("unroll") \
    for (int m_ = 0; m_ < 4; ++m_) \
        _Pragma("unroll") \
        for (int n_ = 0; n_ < 4; ++n_) \
            acc[4 + m_][n_] = __builtin_amdgcn_mfma_f32_16x16x32_bf16( \
                aHi[m_], bFr[n_], acc[4 + m_][n_], 0, 0, 0); \
    __builtin_amdgcn_s_setprio(0); \
} while (0)

// DO_HI_/DO_STAGE_ are compile-time 0/1; VM/BAR handled by caller flags
#define BODY(BUF_, J_, DO_HI_, DO_STAGE_, VM_STMT, DO_BAR_) do { \
    if (DO_HI_) MFMA_HI; \
    READ_LOB(BUF_); \
    if (DO_STAGE_) STAGE(((J_) + 2) & 3, (J_) + 2); \
    READ_HI(BUF_); \
    MFMA_LO; \
    VM_STMT; \
    if (DO_BAR_) __builtin_amdgcn_s_barrier(); \
} while (0)

    // prologue: stage tiles 0,1 (8 loads in flight); prove tile0 landed
    STAGE(0, 0);
    STAGE(1, 1);
    VM4;
    __builtin_amdgcn_s_barrier();

    BODY(0, 0, 0, 1, VM4, 1);                 // j=0 (no HI of tile -1)

#pragma unroll 1
    for (int j4 = 1; j4 < 61; j4 += 4) {      // j = 1..60
        BODY(1, j4 + 0, 1, 1, VM4, 1);
        BODY(2, j4 + 1, 1, 1, VM4, 1);
        BODY(3, j4 + 2, 1, 1, VM4, 1);
        BODY(0, j4 + 3, 1, 1, VM4, 1);
    }
    BODY(1, 61, 1, 1, VM4, 1);                // stages tile 63
    BODY(2, 62, 1, 0, VM0, 1);                // tile 63 proven landed
    BODY(3, 63, 1, 0, NOOP, 0);               // last LO; no sync needed
    MFMA_HI;                                  // tile 63 HI

    // epilogue: C/D layout col=lane&15, row=(lane>>4)*4+reg (R1-verified)
#pragma unroll
    for (int m = 0; m < 8; ++m) {
        const int row0 = bm + wr * 128 + m * 16 + lq * 4;
#pragma unroll
        for (int n = 0; n < 4; ++n) {
            const int col = bn + wc * 64 + n * 16 + lr;
#pragma unroll
            for (int j = 0; j < 4; ++j)
                Ob[(size_t)(row0 + j) * NDIM + col] = acc[m][n][j];
        }
    }
#undef BODY
#undef MFMA_HI
#undef MFMA_LO
#undef READ_HI
#undef READ_LOB
#undef STAGE
}

// ---------------- Fallback: R1 fused kernel (proven) --------------------
__device__ __forceinline__ unsigned short f2bf(float f) {
    unsigned int u = __builtin_bit_cast(unsigned int, f);
    u += 0x7fffu + ((u >> 16) & 1u);
    return (unsigned short)(u >> 16);
}

__global__ __launch_bounds__(256, 2)
void bgemm_fused(const float* __restrict__ A, const float* __restrict__ B,
                 float* __restrict__ O) {
    __shared__ alignas(16) unsigned short Asl[2][4 * 128 * 8];
    __shared__ alignas(16) unsigned short Bsl[2][4 * 128 * 8];
    const int tid = threadIdx.x;
    const int gid = blockIdx.x;
    const int batch = gid & 7;
    const int t = gid >> 3;
    const int bm = (t >> 4) * 128;
    const int bn = (t & 15) * 128;
    const float* Ab = A + (size_t)batch * SDIM * KDIM;
    const float* Bb = B + (size_t)batch * KDIM * NDIM;
    float* Ob = O + (size_t)batch * SDIM * NDIM;
    const int lane = tid & 63;
    const int wid = tid >> 6;
    const int wr = wid >> 1, wc = wid & 1;
    const int lr = lane & 15, lq = lane >> 4;
    const int r0 = tid & 127, h0 = tid >> 7;
    u16x8 areg[2], breg[2];
    f32x4 acc[4][4];
#pragma unroll
    for (int m = 0; m < 4; ++m)
#pragma unroll
        for (int n = 0; n < 4; ++n) acc[m][n] = (f32x4){0.f, 0.f, 0.f, 0.f};
    auto stage_regs = [&](int kt) {
        const int k0 = kt * 32;
        const float* ap = Ab + (size_t)(bm + r0) * KDIM + k0 + h0 * 16;
        float4 a0 = *reinterpret_cast<const float4*>(ap + 0);
        float4 a1 = *reinterpret_cast<const float4*>(ap + 4);
        float4 a2 = *reinterpret_cast<const float4*>(ap + 8);
        float4 a3 = *reinterpret_cast<const float4*>(ap + 12);
        u16x8 u;
        u[0]=f2bf(a0.x);u[1]=f2bf(a0.y);u[2]=f2bf(a0.z);u[3]=f2bf(a0.w);
        u[4]=f2bf(a1.x);u[5]=f2bf(a1.y);u[6]=f2bf(a1.z);u[7]=f2bf(a1.w);
        areg[0]=u;
        u[0]=f2bf(a2.x);u[1]=f2bf(a2.y);u[2]=f2bf(a2.z);u[3]=f2bf(a2.w);
        u[4]=f2bf(a3.x);u[5]=f2bf(a3.y);u[6]=f2bf(a3.z);u[7]=f2bf(a3.w);
        areg[1]=u;
        const float* bp = Bb + (size_t)(k0 + h0 * 16) * NDIM + bn + r0;
        float f[16];
#pragma unroll
        for (int j = 0; j < 16; ++j) f[j] = bp[(size_t)j * NDIM];
        u16x8 v;
#pragma unroll
        for (int j = 0; j < 8; ++j) v[j] = f2bf(f[j]);
        breg[0] = v;
#pragma unroll
        for (int j = 0; j < 8; ++j) v[j] = f2bf(f[8 + j]);
        breg[1] = v;
    };
    auto regs_to_lds = [&](int b) {
#pragma unroll
        for (int o = 0; o < 2; ++o) {
            *reinterpret_cast<u16x8*>(&Asl[b][((h0*2+o)*128 + r0)*8]) = areg[o];
            *reinterpret_cast<u16x8*>(&Bsl[b][((h0*2+o)*128 + r0)*8]) = breg[o];
        }
    };
    stage_regs(0);
    regs_to_lds(0);
    int buf = 0;
    for (int kt = 0; kt < KDIM / 32; ++kt) {
        if (kt + 1 < KDIM / 32) stage_regs(kt + 1);
        __syncthreads();
        bf16x8 af[4], bfv[4];
#pragma unroll
        for (int m = 0; m < 4; ++m)
            af[m] = *reinterpret_cast<const bf16x8*>(&Asl[buf][(lq*128 + wr*64 + m*16 + lr)*8]);
#pragma unroll
        for (int n = 0; n < 4; ++n)
            bfv[n] = *reinterpret_cast<const bf16x8*>(&Bsl[buf][(lq*128 + wc*64 + n*16 + lr)*8]);
#pragma unroll
        for (int m = 0; m < 4; ++m)
#pragma unroll
            for (int n = 0; n < 4; ++n)
                acc[m][n] = __builtin_amdgcn_mfma_f32_16x16x32_bf16(af[m], bfv[n], acc[m][n], 0, 0, 0);
        if (kt + 1 < KDIM / 32) regs_to_lds(buf ^ 1);
        buf ^= 1;
    }
#pragma unroll
    for (int m = 0; m < 4; ++m) {
        const int row0 = bm + wr * 64 + m * 16 + lq * 4;
#pragma unroll
        for (int n = 0; n < 4; ++n) {
            const int col = bn + wc * 64 + n * 16 + lr;
#pragma unroll
            for (int j = 0; j < 4; ++j)
                Ob[(size_t)(row0 + j) * NDIM + col] = acc[m][n][j];
        }
    }
}

extern "C" void kernel_launch(void* const* d_in, const int* in_sizes, int n_in,
                              void* d_out, int out_size, void* d_ws, size_t ws_size,
                              hipStream_t stream) {
    const float* a = (const float*)d_in[0];
    const float* b = (const float*)d_in[1];
    float* o = (float*)d_out;
    const size_t half = (size_t)BATCH * SDIM * KDIM * sizeof(bf16_t);  // 64 MiB
    if (ws_size >= 2 * half) {
        bf16_t* Abf = (bf16_t*)d_ws;
        bf16_t* Bt = (bf16_t*)((char*)d_ws + half);
        hipLaunchKernelGGL(cvtA_kernel, dim3(4096), dim3(256), 0, stream, a, Abf);
        hipLaunchKernelGGL(cvtBT_kernel, dim3(8192), dim3(256), 0, stream, b, Bt);
        hipLaunchKernelGGL(bgemm_pipe, dim3(512), dim3(512), 0, stream, Abf, Bt, o);
    } else {
        hipLaunchKernelGGL(bgemm_fused, dim3(2048), dim3(256), 0, stream, a, b, o);
    }
}